// Round 6
// baseline (308.784 us; speedup 1.0000x reference)
//
#include <hip/hip_runtime.h>
#include <hip/hip_bf16.h>

#define DEVI __device__ __forceinline__

constexpr int Bc = 2, Cc = 64, Tc = 4, Hc = 64, Wc = 64, OFFc = 54, KVc = 27;
constexpr int HW  = Hc * Wc;     // 4096
constexpr int THW = Tc * HW;     // 16384

typedef __attribute__((ext_vector_type(8))) short bf16x8;
typedef __attribute__((ext_vector_type(4))) float f32x4;

DEVI short f2bf(float f) {
    __hip_bfloat16 h = __float2bfloat16(f);
    return *reinterpret_cast<short*>(&h);
}
DEVI float bf2f(short s) {
    unsigned u = ((unsigned)(unsigned short)s) << 16;
    float f; __builtin_memcpy(&f, &u, 4); return f;
}

// ------- weights -> K-major MFMA A layout -------
// wAk[((tap*2+ch)*4+mf)*512 + l15*32 + q] = w[o=mf*16+l15][c=ch*32+q][tap]
__global__ __launch_bounds__(256) void w_prep(const float* __restrict__ w,
                                              __hip_bfloat16* __restrict__ wAk, int ovalid) {
    int i = blockIdx.x * 256 + threadIdx.x;   // 216*512 = 110592
    if (i >= 216 * 512) return;
    int u = i >> 9, r = i & 511;
    int mf = u & 3, ch = (u >> 2) & 1, tap = u >> 3;
    int o = mf * 16 + (r >> 5), c = ch * 32 + (r & 31);
    float v = (o < ovalid) ? w[(o * Cc + c) * KVc + tap] : 0.f;
    wAk[i] = __float2bfloat16(v);
}

// ------- cast + transpose to channel-last bf16: x[b][c][t][h][w] -> xcl[b][t][h][w][c] -------
__global__ __launch_bounds__(256) void cast_cl(const float* __restrict__ x,
                                               __hip_bfloat16* __restrict__ xcl) {
    __shared__ float s[64][65];
    int tid = threadIdx.x;
    int bi  = blockIdx.x;
    int h = bi & 63, t = (bi >> 6) & 3, b = bi >> 8;

    const float* xp = x + (size_t)b * Cc * THW + t * HW + h * 64;
    int w0 = tid & 63, c0 = tid >> 6;
    #pragma unroll
    for (int i = 0; i < 16; ++i) {
        int c = c0 + i * 4;
        s[c][w0] = xp[(size_t)c * THW + w0];
    }
    __syncthreads();

    __hip_bfloat16* dst = xcl + (((size_t)b * Tc + t) * HW + (size_t)h * 64) * 64;
    #pragma unroll
    for (int r = 0; r < 2; ++r) {
        int j  = tid + r * 256;
        int w  = j >> 3;
        int c8 = j & 7;
        bf16x8 v;
        #pragma unroll
        for (int jj = 0; jj < 8; ++jj)
            v[jj] = f2bf(s[c8 * 8 + jj][w]);
        *reinterpret_cast<bf16x8*>(dst + w * 64 + c8 * 8) = v;
    }
}

// ================= fused offset-conv + deformable-conv =================
// block = (b,t,h,quarter-row): 16 positions. 4 waves = tap-half (wv&1) x
// channel-half (wv>>1) K-split. Phase1: offset conv MFMA -> s_off.
// Phase2: bilinear-sample implicit GEMM MFMA -> s_red -> fused epilogue.
template <bool L2>
__global__ __launch_bounds__(256, 8) void fused_deform(
    const __hip_bfloat16* __restrict__ src, const __hip_bfloat16* __restrict__ owAk,
    const float* __restrict__ obias, const __hip_bfloat16* __restrict__ wAk,
    const float* __restrict__ xres, float* __restrict__ outf,
    __hip_bfloat16* __restrict__ ycl)
{
    __shared__ float s_off[KVc][2][18];
    __shared__ float s_red[16 * 68];

    int tid = threadIdx.x;
    int wv = tid >> 6, lane = tid & 63, l15 = lane & 15, l4 = lane >> 4;
    int th = wv & 1, chh = wv >> 1;
    int bi = blockIdx.x;
    int q4 = bi & 3, h = (bi >> 2) & 63, t = (bi >> 8) & 3, b = bi >> 10;

    int p0 = q4 << 4;
    int p  = p0 + l15;               // global w position
    int cbase = chh * 32 + l4 * 8;   // channel slice of this wave
    int tap0 = th ? 14 : 0, tap1 = th ? 27 : 14;

    // ---- phase 0: init s_off with bias, zero s_red ----
    for (int i = tid; i < KVc * 2 * 18; i += 256) {
        int k = i / 36, rem = i - k * 36, j = rem / 18;
        s_off[0][0][i] = obias[2 * k + j];   // pad entries get junk bias; never read
    }
    for (int i = tid; i < 16 * 68; i += 256) s_red[i] = 0.f;
    __syncthreads();

    const __hip_bfloat16* xb = src + ((size_t)b << 20);

    // ---- phase 1: offset conv (M=64/54 x N=16, K split 4-ways) ----
    {
        f32x4 cacc[4];
        #pragma unroll
        for (int mf = 0; mf < 4; ++mf) cacc[mf] = (f32x4){0.f, 0.f, 0.f, 0.f};

        for (int tap = tap0; tap < tap1; ++tap) {
            int kt = tap / 9, rr = tap - kt * 9, kh = rr / 3, kw = rr - kh * 3;
            int tt = t + kt - 1, hh = h + kh - 1;
            bool rowok = (unsigned)tt < 4u && (unsigned)hh < 64u;
            int ws = p + kw - 1;
            bf16x8 bv = {0, 0, 0, 0, 0, 0, 0, 0};
            if (rowok && (unsigned)ws < 64u)
                bv = *reinterpret_cast<const bf16x8*>(xb + (((size_t)tt * HW + hh * 64 + ws) << 6) + cbase);
            const __hip_bfloat16* ab = owAk + ((tap * 2 + chh) << 11) + (l15 << 5) + (l4 << 3);
            #pragma unroll
            for (int mf = 0; mf < 4; ++mf) {
                bf16x8 af = *reinterpret_cast<const bf16x8*>(ab + (mf << 9));
                cacc[mf] = __builtin_amdgcn_mfma_f32_16x16x32_bf16(af, bv, cacc[mf], 0, 0, 0);
            }
        }
        #pragma unroll
        for (int mf = 0; mf < 4; ++mf)
            #pragma unroll
            for (int jj = 0; jj < 4; ++jj) {
                int o = mf * 16 + l4 * 4 + jj;
                if (o < OFFc) atomicAdd(&s_off[o >> 1][o & 1][l15], cacc[mf][jj]);
            }
    }
    __syncthreads();

    // ---- phase 2: deformable conv, software-pipelined over this wave's taps ----
    f32x4 dacc[4];
    #pragma unroll
    for (int mf = 0; mf < 4; ++mf) dacc[mf] = (f32x4){0.f, 0.f, 0.f, 0.f};

    auto issue = [&](int tap, bf16x8 (&g)[4], float (&cf)[4]) {
        int kt = tap / 9, rr = tap - kt * 9, kh = rr / 3, kw = rr - kh * 3;
        int tt = t + kt - 1;
        float tm = ((unsigned)tt < 4u) ? 1.f : 0.f;
        int tic = min(max(tt, 0), 3);
        const __hip_bfloat16* xt = xb + ((size_t)tic << 18);
        float dh = s_off[tap][0][l15], dw = s_off[tap][1][l15];
        float hs  = (float)(h + kh - 1) + dh;
        float wsf = (float)(p + kw - 1) + dw;
        float fh = floorf(hs), fw = floorf(wsf);
        int h0 = (int)fh, w0 = (int)fw, h1 = h0 + 1, w1 = w0 + 1;
        float lh = hs - fh, lw = wsf - fw;
        float u0 = (1.f - lh) * (((unsigned)h0 < 64u) ? tm : 0.f);
        float u1 = lh         * (((unsigned)h1 < 64u) ? tm : 0.f);
        float q0 = (1.f - lw) * (((unsigned)w0 < 64u) ? 1.f : 0.f);
        float q1 = lw         * (((unsigned)w1 < 64u) ? 1.f : 0.f);
        cf[0] = u0 * q0; cf[1] = u0 * q1; cf[2] = u1 * q0; cf[3] = u1 * q1;
        int hc0 = min(max(h0, 0), 63), hc1 = min(max(h1, 0), 63);
        int wc0 = min(max(w0, 0), 63), wc1 = min(max(w1, 0), 63);
        g[0] = *reinterpret_cast<const bf16x8*>(xt + ((hc0 * 64 + wc0) << 6) + cbase);
        g[1] = *reinterpret_cast<const bf16x8*>(xt + ((hc0 * 64 + wc1) << 6) + cbase);
        g[2] = *reinterpret_cast<const bf16x8*>(xt + ((hc1 * 64 + wc0) << 6) + cbase);
        g[3] = *reinterpret_cast<const bf16x8*>(xt + ((hc1 * 64 + wc1) << 6) + cbase);
    };
    auto consume = [&](int tap, bf16x8 (&g)[4], float (&cf)[4]) {
        bf16x8 bfrag;
        #pragma unroll
        for (int j = 0; j < 8; ++j) {
            float s = cf[0] * bf2f(g[0][j]) + cf[1] * bf2f(g[1][j])
                    + cf[2] * bf2f(g[2][j]) + cf[3] * bf2f(g[3][j]);
            bfrag[j] = f2bf(s);
        }
        const __hip_bfloat16* ab = wAk + ((tap * 2 + chh) << 11) + (l15 << 5) + (l4 << 3);
        #pragma unroll
        for (int mf = 0; mf < 4; ++mf) {
            bf16x8 af = *reinterpret_cast<const bf16x8*>(ab + (mf << 9));
            dacc[mf] = __builtin_amdgcn_mfma_f32_16x16x32_bf16(af, bfrag, dacc[mf], 0, 0, 0);
        }
    };

    bf16x8 gA[4], gB[4];
    float  cA[4], cB[4];
    issue(tap0, gA, cA);
    int tap = tap0;
    for (; tap + 2 <= tap1; tap += 2) {
        issue(tap + 1, gB, cB);
        consume(tap, gA, cA);
        if (tap + 2 < tap1) issue(tap + 2, gA, cA);
        consume(tap + 1, gB, cB);
    }
    if (tap < tap1) consume(tap, gA, cA);   // odd tap-count tail

    #pragma unroll
    for (int mf = 0; mf < 4; ++mf)
        #pragma unroll
        for (int jj = 0; jj < 4; ++jj) {
            int o = mf * 16 + l4 * 4 + jj;
            atomicAdd(&s_red[l15 * 68 + o], dacc[mf][jj]);
        }
    __syncthreads();

    // ---- phase 3: fused epilogue ----
    if (!L2) {
        // leaky-relu + channel-last bf16 store (feeds layer-2 conv + sampling)
        if (tid < 128) {
            int pp = tid >> 3, o8 = (tid & 7) << 3;
            __hip_bfloat16* dst = ycl + ((((size_t)b * Tc + t) * HW + h * 64 + p0 + pp) << 6) + o8;
            bf16x8 o8v;
            #pragma unroll
            for (int j = 0; j < 8; ++j) {
                float v = s_red[pp * 68 + o8 + j];
                v = v >= 0.f ? v : 0.1f * v;
                o8v[j] = f2bf(v);
            }
            *reinterpret_cast<bf16x8*>(dst) = o8v;
        }
    } else {
        // residual add + fp32 channel-first store
        int o = tid >> 2, pg = (tid & 3) << 2;
        size_t base = ((size_t)(b * Cc + o) * Tc + t) * HW + h * 64 + p0 + pg;
        f32x4 r, xv = *reinterpret_cast<const f32x4*>(xres + base);
        #pragma unroll
        for (int j = 0; j < 4; ++j) r[j] = s_red[(pg + j) * 68 + o] + xv[j];
        *reinterpret_cast<f32x4*>(outf + base) = r;
    }
}

extern "C" void kernel_launch(void* const* d_in, const int* in_sizes, int n_in,
                              void* d_out, int out_size, void* d_ws, size_t ws_size,
                              hipStream_t stream)
{
    const float* x   = (const float*)d_in[0];
    const float* w0  = (const float*)d_in[1];
    const float* ow0 = (const float*)d_in[2];
    const float* ob0 = (const float*)d_in[3];
    const float* w1  = (const float*)d_in[4];
    const float* ow1 = (const float*)d_in[5];
    const float* ob1 = (const float*)d_in[6];
    float* out = (float*)d_out;

    // ws layout (bf16): xcl 2M, ycl 2M, 4 weight buffers 110592 each => ~8.8 MB total
    __hip_bfloat16* xcl  = (__hip_bfloat16*)d_ws;
    __hip_bfloat16* ycl  = xcl  + (size_t)Bc * THW * 64;
    __hip_bfloat16* owA0 = ycl  + (size_t)Bc * THW * 64;
    __hip_bfloat16* owA1 = owA0 + (size_t)216 * 512;
    __hip_bfloat16* wA0  = owA1 + (size_t)216 * 512;
    __hip_bfloat16* wA1  = wA0  + (size_t)216 * 512;

    w_prep<<<432, 256, 0, stream>>>(ow0, owA0, OFFc);
    w_prep<<<432, 256, 0, stream>>>(ow1, owA1, OFFc);
    w_prep<<<432, 256, 0, stream>>>(w0,  wA0,  Cc);
    w_prep<<<432, 256, 0, stream>>>(w1,  wA1,  Cc);
    cast_cl<<<512, 256, 0, stream>>>(x, xcl);

    fused_deform<false><<<2048, 256, 0, stream>>>(xcl, owA0, ob0, wA0, nullptr, nullptr, ycl);
    fused_deform<true><<<2048, 256, 0, stream>>>(ycl, owA1, ob1, wA1, x, out, nullptr);
}

// Round 7
// 272.991 us; speedup vs baseline: 1.1311x; 1.1311x over previous
//
#include <hip/hip_runtime.h>
#include <hip/hip_bf16.h>

#define DEVI __device__ __forceinline__

constexpr int Bc = 2, Cc = 64, Tc = 4, Hc = 64, Wc = 64, OFFc = 54, KVc = 27;
constexpr int HW  = Hc * Wc;     // 4096
constexpr int THW = Tc * HW;     // 16384

typedef __attribute__((ext_vector_type(8))) short bf16x8;
typedef __attribute__((ext_vector_type(4))) float f32x4;

DEVI short f2bf(float f) {
    __hip_bfloat16 h = __float2bfloat16(f);
    return *reinterpret_cast<short*>(&h);
}
DEVI float bf2f(short s) {
    unsigned u = ((unsigned)(unsigned short)s) << 16;
    float f; __builtin_memcpy(&f, &u, 4); return f;
}

// ------- weights -> K-major MFMA A layout -------
// wAk[((tap*2+ch)*4+mf)*512 + l15*32 + q] = w[o=mf*16+l15][c=ch*32+q][tap]
__global__ __launch_bounds__(256) void w_prep(const float* __restrict__ w,
                                              __hip_bfloat16* __restrict__ wAk, int ovalid) {
    int i = blockIdx.x * 256 + threadIdx.x;   // 216*512 = 110592
    if (i >= 216 * 512) return;
    int u = i >> 9, r = i & 511;
    int mf = u & 3, ch = (u >> 2) & 1, tap = u >> 3;
    int o = mf * 16 + (r >> 5), c = ch * 32 + (r & 31);
    float v = (o < ovalid) ? w[(o * Cc + c) * KVc + tap] : 0.f;
    wAk[i] = __float2bfloat16(v);
}

// ------- cast + transpose to channel-last bf16: x[b][c][t][h][w] -> xcl[b][t][h][w][c] -------
__global__ __launch_bounds__(256) void cast_cl(const float* __restrict__ x,
                                               __hip_bfloat16* __restrict__ xcl) {
    __shared__ float s[64][65];
    int tid = threadIdx.x;
    int bi  = blockIdx.x;
    int h = bi & 63, t = (bi >> 6) & 3, b = bi >> 8;

    const float* xp = x + (size_t)b * Cc * THW + t * HW + h * 64;
    int w0 = tid & 63, c0 = tid >> 6;
    #pragma unroll
    for (int i = 0; i < 16; ++i) {
        int c = c0 + i * 4;
        s[c][w0] = xp[(size_t)c * THW + w0];
    }
    __syncthreads();

    __hip_bfloat16* dst = xcl + (((size_t)b * Tc + t) * HW + (size_t)h * 64) * 64;
    #pragma unroll
    for (int r = 0; r < 2; ++r) {
        int j  = tid + r * 256;
        int w  = j >> 3;
        int c8 = j & 7;
        bf16x8 v;
        #pragma unroll
        for (int jj = 0; jj < 8; ++jj)
            v[jj] = f2bf(s[c8 * 8 + jj][w]);
        *reinterpret_cast<bf16x8*>(dst + w * 64 + c8 * 8) = v;
    }
}

// ================= fused offset-conv + deformable-conv =================
// block = (b,t,h,half-row): 32 positions. 4 waves: nf = wv&1 (16-pos group),
// chh = wv>>1 (K channel-half).
// XCD swizzle: blockIdx = j*8 + (b*4+t)  => all blocks of one (b,t) plane land
// on one XCD (blockIdx%8 round-robin); plane slab (~1.5MB incl. t+-1) fits its 4MB L2.
template <bool L2>
__global__ __launch_bounds__(256, 4) void fused_deform(
    const __hip_bfloat16* __restrict__ src, const __hip_bfloat16* __restrict__ owAk,
    const float* __restrict__ obias, const __hip_bfloat16* __restrict__ wAk,
    const float* __restrict__ xres, float* __restrict__ outf,
    __hip_bfloat16* __restrict__ ycl)
{
    __shared__ float s_off[KVc][2][34];
    __shared__ float s_red[32 * 68];

    int tid = threadIdx.x;
    int wv = tid >> 6, lane = tid & 63, l15 = lane & 15, l4 = lane >> 4;
    int nf = wv & 1, chh = wv >> 1;
    int bi = blockIdx.x;
    int pid = bi & 7;                // (b,t) plane -> XCD via %8 round-robin
    int j   = bi >> 3;               // 0..127 within plane
    int half = j & 1, h = j >> 1;
    int b = pid >> 2, t = pid & 3;

    int pl = l15 + nf * 16;          // local position 0..31
    int p  = pl + half * 32;         // global w position 0..63
    int cbase = chh * 32 + l4 * 8;   // channel slice of this wave

    // ---- phase 0: init s_off with bias, zero s_red ----
    for (int i = tid; i < KVc * 2 * 34; i += 256) {
        int k = i / 68, rem = i - k * 68, jj = rem / 34, pp = rem - jj * 34;
        s_off[k][jj][pp] = obias[2 * k + jj];
    }
    for (int i = tid; i < 32 * 68; i += 256) s_red[i] = 0.f;
    __syncthreads();

    const __hip_bfloat16* xb = src + ((size_t)b << 20);

    // ---- phase 1: offset conv (M=64/54 x N=16 per wave x K=864 per wave) ----
    {
        f32x4 cacc[4];
        #pragma unroll
        for (int mf = 0; mf < 4; ++mf) cacc[mf] = (f32x4){0.f, 0.f, 0.f, 0.f};

        #pragma unroll 3
        for (int tap = 0; tap < KVc; ++tap) {
            int kt = tap / 9, rr = tap - kt * 9, kh = rr / 3, kw = rr - kh * 3;
            int tt = t + kt - 1, hh = h + kh - 1;
            bool rowok = (unsigned)tt < 4u && (unsigned)hh < 64u;
            int ws = p + kw - 1;
            bf16x8 bv = {0, 0, 0, 0, 0, 0, 0, 0};
            if (rowok && (unsigned)ws < 64u)
                bv = *reinterpret_cast<const bf16x8*>(xb + (((size_t)tt * HW + hh * 64 + ws) << 6) + cbase);
            const __hip_bfloat16* ab = owAk + ((tap * 2 + chh) << 11) + (l15 << 5) + (l4 << 3);
            #pragma unroll
            for (int mf = 0; mf < 4; ++mf) {
                bf16x8 af = *reinterpret_cast<const bf16x8*>(ab + (mf << 9));
                cacc[mf] = __builtin_amdgcn_mfma_f32_16x16x32_bf16(af, bv, cacc[mf], 0, 0, 0);
            }
        }
        #pragma unroll
        for (int mf = 0; mf < 4; ++mf)
            #pragma unroll
            for (int jj = 0; jj < 4; ++jj) {
                int o = mf * 16 + l4 * 4 + jj;
                if (o < OFFc) atomicAdd(&s_off[o >> 1][o & 1][pl], cacc[mf][jj]);
            }
    }
    __syncthreads();

    // ---- phase 2: deformable conv, software-pipelined over taps ----
    f32x4 dacc[4];
    #pragma unroll
    for (int mf = 0; mf < 4; ++mf) dacc[mf] = (f32x4){0.f, 0.f, 0.f, 0.f};

    auto issue = [&](int tap, bf16x8 (&g)[4], float (&cf)[4]) {
        int kt = tap / 9, rr = tap - kt * 9, kh = rr / 3, kw = rr - kh * 3;
        int tt = t + kt - 1;
        float tm = ((unsigned)tt < 4u) ? 1.f : 0.f;
        int tic = min(max(tt, 0), 3);
        const __hip_bfloat16* xt = xb + ((size_t)tic << 18);
        float dh = s_off[tap][0][pl], dw = s_off[tap][1][pl];
        float hs  = (float)(h + kh - 1) + dh;
        float wsf = (float)(p + kw - 1) + dw;
        float fh = floorf(hs), fw = floorf(wsf);
        int h0 = (int)fh, w0 = (int)fw, h1 = h0 + 1, w1 = w0 + 1;
        float lh = hs - fh, lw = wsf - fw;
        float u0 = (1.f - lh) * (((unsigned)h0 < 64u) ? tm : 0.f);
        float u1 = lh         * (((unsigned)h1 < 64u) ? tm : 0.f);
        float q0 = (1.f - lw) * (((unsigned)w0 < 64u) ? 1.f : 0.f);
        float q1 = lw         * (((unsigned)w1 < 64u) ? 1.f : 0.f);
        cf[0] = u0 * q0; cf[1] = u0 * q1; cf[2] = u1 * q0; cf[3] = u1 * q1;
        int hc0 = min(max(h0, 0), 63), hc1 = min(max(h1, 0), 63);
        int wc0 = min(max(w0, 0), 63), wc1 = min(max(w1, 0), 63);
        g[0] = *reinterpret_cast<const bf16x8*>(xt + ((hc0 * 64 + wc0) << 6) + cbase);
        g[1] = *reinterpret_cast<const bf16x8*>(xt + ((hc0 * 64 + wc1) << 6) + cbase);
        g[2] = *reinterpret_cast<const bf16x8*>(xt + ((hc1 * 64 + wc0) << 6) + cbase);
        g[3] = *reinterpret_cast<const bf16x8*>(xt + ((hc1 * 64 + wc1) << 6) + cbase);
    };
    auto consume = [&](int tap, bf16x8 (&g)[4], float (&cf)[4]) {
        bf16x8 bfrag;
        #pragma unroll
        for (int jj = 0; jj < 8; ++jj) {
            float s = cf[0] * bf2f(g[0][jj]) + cf[1] * bf2f(g[1][jj])
                    + cf[2] * bf2f(g[2][jj]) + cf[3] * bf2f(g[3][jj]);
            bfrag[jj] = f2bf(s);
        }
        const __hip_bfloat16* ab = wAk + ((tap * 2 + chh) << 11) + (l15 << 5) + (l4 << 3);
        #pragma unroll
        for (int mf = 0; mf < 4; ++mf) {
            bf16x8 af = *reinterpret_cast<const bf16x8*>(ab + (mf << 9));
            dacc[mf] = __builtin_amdgcn_mfma_f32_16x16x32_bf16(af, bfrag, dacc[mf], 0, 0, 0);
        }
    };

    bf16x8 gA[4], gB[4];
    float  cA[4], cB[4];
    issue(0, gA, cA);
    for (int tap = 0; tap + 2 <= KVc; tap += 2) {
        issue(tap + 1, gB, cB);
        consume(tap, gA, cA);
        if (tap + 2 < KVc) issue(tap + 2, gA, cA);
        consume(tap + 1, gB, cB);
    }
    consume(KVc - 1, gA, cA);   // tap 26 (issued in last loop iter)

    #pragma unroll
    for (int mf = 0; mf < 4; ++mf)
        #pragma unroll
        for (int jj = 0; jj < 4; ++jj) {
            int o = mf * 16 + l4 * 4 + jj;
            atomicAdd(&s_red[pl * 68 + o], dacc[mf][jj]);
        }
    __syncthreads();

    // ---- phase 3: fused epilogue ----
    if (!L2) {
        // leaky-relu + channel-last bf16 store (feeds layer-2 conv + sampling)
        int pp = tid >> 3, o8 = (tid & 7) << 3;
        __hip_bfloat16* dst = ycl + ((((size_t)b * Tc + t) * HW + h * 64 + half * 32 + pp) << 6) + o8;
        bf16x8 o8v;
        #pragma unroll
        for (int jj = 0; jj < 8; ++jj) {
            float v = s_red[pp * 68 + o8 + jj];
            v = v >= 0.f ? v : 0.1f * v;
            o8v[jj] = f2bf(v);
        }
        *reinterpret_cast<bf16x8*>(dst) = o8v;
    } else {
        // residual add + fp32 channel-first store
        int o = tid >> 2, pg = (tid & 3) << 3;
        size_t base = ((size_t)(b * Cc + o) * Tc + t) * HW + h * 64 + half * 32 + pg;
        #pragma unroll
        for (int q = 0; q < 2; ++q) {
            f32x4 r, xv = *reinterpret_cast<const f32x4*>(xres + base + q * 4);
            #pragma unroll
            for (int jj = 0; jj < 4; ++jj) r[jj] = s_red[(pg + q * 4 + jj) * 68 + o] + xv[jj];
            *reinterpret_cast<f32x4*>(outf + base + q * 4) = r;
        }
    }
}

extern "C" void kernel_launch(void* const* d_in, const int* in_sizes, int n_in,
                              void* d_out, int out_size, void* d_ws, size_t ws_size,
                              hipStream_t stream)
{
    const float* x   = (const float*)d_in[0];
    const float* w0  = (const float*)d_in[1];
    const float* ow0 = (const float*)d_in[2];
    const float* ob0 = (const float*)d_in[3];
    const float* w1  = (const float*)d_in[4];
    const float* ow1 = (const float*)d_in[5];
    const float* ob1 = (const float*)d_in[6];
    float* out = (float*)d_out;

    // ws layout (bf16): xcl 2M, ycl 2M, 4 weight buffers 110592 each => ~8.8 MB total
    __hip_bfloat16* xcl  = (__hip_bfloat16*)d_ws;
    __hip_bfloat16* ycl  = xcl  + (size_t)Bc * THW * 64;
    __hip_bfloat16* owA0 = ycl  + (size_t)Bc * THW * 64;
    __hip_bfloat16* owA1 = owA0 + (size_t)216 * 512;
    __hip_bfloat16* wA0  = owA1 + (size_t)216 * 512;
    __hip_bfloat16* wA1  = wA0  + (size_t)216 * 512;

    w_prep<<<432, 256, 0, stream>>>(ow0, owA0, OFFc);
    w_prep<<<432, 256, 0, stream>>>(ow1, owA1, OFFc);
    w_prep<<<432, 256, 0, stream>>>(w0,  wA0,  Cc);
    w_prep<<<432, 256, 0, stream>>>(w1,  wA1,  Cc);
    cast_cl<<<512, 256, 0, stream>>>(x, xcl);

    fused_deform<false><<<1024, 256, 0, stream>>>(xcl, owA0, ob0, wA0, nullptr, nullptr, ycl);
    fused_deform<true><<<1024, 256, 0, stream>>>(ycl, owA1, ob1, wA1, x, out, nullptr);
}

// Round 8
// 261.980 us; speedup vs baseline: 1.1787x; 1.0420x over previous
//
#include <hip/hip_runtime.h>
#include <hip/hip_bf16.h>

#define DEVI __device__ __forceinline__

constexpr int Bc = 2, Cc = 64, Tc = 4, Hc = 64, Wc = 64, OFFc = 54, KVc = 27;
constexpr int HW  = Hc * Wc;     // 4096
constexpr int THW = Tc * HW;     // 16384

typedef __attribute__((ext_vector_type(8))) short bf16x8;
typedef __attribute__((ext_vector_type(4))) float f32x4;

DEVI short f2bf(float f) {
    __hip_bfloat16 h = __float2bfloat16(f);
    return *reinterpret_cast<short*>(&h);
}
DEVI float bf2f(short s) {
    unsigned u = ((unsigned)(unsigned short)s) << 16;
    float f; __builtin_memcpy(&f, &u, 4); return f;
}

// ------- weights -> K-major MFMA A layout -------
// wAk[((tap*2+ch)*4+mf)*512 + l15*32 + q] = w[o=mf*16+l15][c=ch*32+q][tap]
__global__ __launch_bounds__(256) void w_prep(const float* __restrict__ w,
                                              __hip_bfloat16* __restrict__ wAk, int ovalid) {
    int i = blockIdx.x * 256 + threadIdx.x;   // 216*512 = 110592
    if (i >= 216 * 512) return;
    int u = i >> 9, r = i & 511;
    int mf = u & 3, ch = (u >> 2) & 1, tap = u >> 3;
    int o = mf * 16 + (r >> 5), c = ch * 32 + (r & 31);
    float v = (o < ovalid) ? w[(o * Cc + c) * KVc + tap] : 0.f;
    wAk[i] = __float2bfloat16(v);
}

// ------- cast + transpose to channel-last bf16: x[b][c][t][h][w] -> xcl[b][t][h][w][c] -------
__global__ __launch_bounds__(256) void cast_cl(const float* __restrict__ x,
                                               __hip_bfloat16* __restrict__ xcl) {
    __shared__ float s[64][65];
    int tid = threadIdx.x;
    int bi  = blockIdx.x;
    int h = bi & 63, t = (bi >> 6) & 3, b = bi >> 8;

    const float* xp = x + (size_t)b * Cc * THW + t * HW + h * 64;
    int w0 = tid & 63, c0 = tid >> 6;
    #pragma unroll
    for (int i = 0; i < 16; ++i) {
        int c = c0 + i * 4;
        s[c][w0] = xp[(size_t)c * THW + w0];
    }
    __syncthreads();

    __hip_bfloat16* dst = xcl + (((size_t)b * Tc + t) * HW + (size_t)h * 64) * 64;
    #pragma unroll
    for (int r = 0; r < 2; ++r) {
        int j  = tid + r * 256;
        int w  = j >> 3;
        int c8 = j & 7;
        bf16x8 v;
        #pragma unroll
        for (int jj = 0; jj < 8; ++jj)
            v[jj] = f2bf(s[c8 * 8 + jj][w]);
        *reinterpret_cast<bf16x8*>(dst + w * 64 + c8 * 8) = v;
    }
}

// ================= fused offset-conv + deformable-conv =================
// block = (b,t,h,half-row): 32 positions. 4 waves: nf = wv&1 (16-pos group),
// chh = wv>>1 (K channel-half).
// XCD swizzle: blockIdx = j*8 + (b*4+t) => plane slab stays in one XCD's L2.
// All vector loads (gathers AND weight fragments) issued one tap ahead so no
// per-tap vmcnt(0) drain; taps with invalid t-plane skipped via uniform [lo,hi).
template <bool L2>
__global__ __launch_bounds__(256, 4) void fused_deform(
    const __hip_bfloat16* __restrict__ src, const __hip_bfloat16* __restrict__ owAk,
    const float* __restrict__ obias, const __hip_bfloat16* __restrict__ wAk,
    const float* __restrict__ xres, float* __restrict__ outf,
    __hip_bfloat16* __restrict__ ycl)
{
    __shared__ float s_off[KVc][2][34];
    __shared__ float s_red[32 * 68];

    int tid = threadIdx.x;
    int wv = tid >> 6, lane = tid & 63, l15 = lane & 15, l4 = lane >> 4;
    int nf = wv & 1, chh = wv >> 1;
    int bi = blockIdx.x;
    int pid = bi & 7;                // (b,t) plane -> XCD via %8 round-robin
    int j   = bi >> 3;               // 0..127 within plane
    int half = j & 1, h = j >> 1;
    int b = pid >> 2, t = pid & 3;

    int pl = l15 + nf * 16;          // local position 0..31
    int p  = pl + half * 32;         // global w position 0..63
    int cbase = chh * 32 + l4 * 8;   // channel slice of this wave

    // valid tap range (t-plane validity is contiguous in tap index)
    int lo = (t == 0) ? 9 : 0;
    int hi = (t == 3) ? 18 : KVc;

    // ---- phase 0: init s_off with bias, zero s_red ----
    for (int i = tid; i < KVc * 2 * 34; i += 256) {
        int k = i / 68, rem = i - k * 68, jj = rem / 34, pp = rem - jj * 34;
        s_off[k][jj][pp] = obias[2 * k + jj];
    }
    for (int i = tid; i < 32 * 68; i += 256) s_red[i] = 0.f;
    __syncthreads();

    const __hip_bfloat16* xb = src + ((size_t)b << 20);

    // ---- phase 1: offset conv, pipelined, weights prefetched with data ----
    {
        f32x4 cacc[4];
        #pragma unroll
        for (int mf = 0; mf < 4; ++mf) cacc[mf] = (f32x4){0.f, 0.f, 0.f, 0.f};

        auto c_issue = [&](int tap, bf16x8 &bv, bf16x8 (&w4)[4]) {
            int kt = tap / 9, rr = tap - kt * 9, kh = rr / 3, kw = rr - kh * 3;
            int tt = t + kt - 1, hh = h + kh - 1;   // tt valid by range
            bool rowok = (unsigned)hh < 64u;
            int ws = p + kw - 1;
            bv = (bf16x8){0, 0, 0, 0, 0, 0, 0, 0};
            if (rowok && (unsigned)ws < 64u)
                bv = *reinterpret_cast<const bf16x8*>(xb + (((size_t)tt * HW + hh * 64 + ws) << 6) + cbase);
            const __hip_bfloat16* ab = owAk + ((tap * 2 + chh) << 11) + (l15 << 5) + (l4 << 3);
            #pragma unroll
            for (int mf = 0; mf < 4; ++mf)
                w4[mf] = *reinterpret_cast<const bf16x8*>(ab + (mf << 9));
        };
        auto c_consume = [&](bf16x8 &bv, bf16x8 (&w4)[4]) {
            #pragma unroll
            for (int mf = 0; mf < 4; ++mf)
                cacc[mf] = __builtin_amdgcn_mfma_f32_16x16x32_bf16(w4[mf], bv, cacc[mf], 0, 0, 0);
        };

        bf16x8 bvA, bvB, wA4[4], wB4[4];
        c_issue(lo, bvA, wA4);
        int tap = lo;
        for (; tap + 2 <= hi; tap += 2) {
            c_issue(tap + 1, bvB, wB4);
            c_consume(bvA, wA4);
            if (tap + 2 < hi) c_issue(tap + 2, bvA, wA4);
            c_consume(bvB, wB4);
        }
        if (tap < hi) c_consume(bvA, wA4);

        #pragma unroll
        for (int mf = 0; mf < 4; ++mf)
            #pragma unroll
            for (int jj = 0; jj < 4; ++jj) {
                int o = mf * 16 + l4 * 4 + jj;
                if (o < OFFc) atomicAdd(&s_off[o >> 1][o & 1][pl], cacc[mf][jj]);
            }
    }
    __syncthreads();

    // ---- phase 2: deformable conv, pipelined, weights prefetched with gathers ----
    f32x4 dacc[4];
    #pragma unroll
    for (int mf = 0; mf < 4; ++mf) dacc[mf] = (f32x4){0.f, 0.f, 0.f, 0.f};

    auto issue = [&](int tap, bf16x8 (&g)[4], bf16x8 (&w4)[4], float (&cf)[4]) {
        int kt = tap / 9, rr = tap - kt * 9, kh = rr / 3, kw = rr - kh * 3;
        int tt = t + kt - 1;                       // valid by range
        const __hip_bfloat16* xt = xb + ((size_t)tt << 18);
        float dh = s_off[tap][0][pl], dw = s_off[tap][1][pl];
        float hs  = (float)(h + kh - 1) + dh;
        float wsf = (float)(p + kw - 1) + dw;
        float fh = floorf(hs), fw = floorf(wsf);
        int h0 = (int)fh, w0 = (int)fw, h1 = h0 + 1, w1 = w0 + 1;
        float lh = hs - fh, lw = wsf - fw;
        float u0 = (1.f - lh) * (((unsigned)h0 < 64u) ? 1.f : 0.f);
        float u1 = lh         * (((unsigned)h1 < 64u) ? 1.f : 0.f);
        float q0 = (1.f - lw) * (((unsigned)w0 < 64u) ? 1.f : 0.f);
        float q1 = lw         * (((unsigned)w1 < 64u) ? 1.f : 0.f);
        cf[0] = u0 * q0; cf[1] = u0 * q1; cf[2] = u1 * q0; cf[3] = u1 * q1;
        int hc0 = min(max(h0, 0), 63), hc1 = min(max(h1, 0), 63);
        int wc0 = min(max(w0, 0), 63), wc1 = min(max(w1, 0), 63);
        g[0] = *reinterpret_cast<const bf16x8*>(xt + ((hc0 * 64 + wc0) << 6) + cbase);
        g[1] = *reinterpret_cast<const bf16x8*>(xt + ((hc0 * 64 + wc1) << 6) + cbase);
        g[2] = *reinterpret_cast<const bf16x8*>(xt + ((hc1 * 64 + wc0) << 6) + cbase);
        g[3] = *reinterpret_cast<const bf16x8*>(xt + ((hc1 * 64 + wc1) << 6) + cbase);
        const __hip_bfloat16* ab = wAk + ((tap * 2 + chh) << 11) + (l15 << 5) + (l4 << 3);
        #pragma unroll
        for (int mf = 0; mf < 4; ++mf)
            w4[mf] = *reinterpret_cast<const bf16x8*>(ab + (mf << 9));
    };
    auto consume = [&](bf16x8 (&g)[4], bf16x8 (&w4)[4], float (&cf)[4]) {
        bf16x8 bfrag;
        #pragma unroll
        for (int jj = 0; jj < 8; ++jj) {
            float s = cf[0] * bf2f(g[0][jj]) + cf[1] * bf2f(g[1][jj])
                    + cf[2] * bf2f(g[2][jj]) + cf[3] * bf2f(g[3][jj]);
            bfrag[jj] = f2bf(s);
        }
        #pragma unroll
        for (int mf = 0; mf < 4; ++mf)
            dacc[mf] = __builtin_amdgcn_mfma_f32_16x16x32_bf16(w4[mf], bfrag, dacc[mf], 0, 0, 0);
    };

    {
        bf16x8 gA[4], gB[4], wA4[4], wB4[4];
        float  cA[4], cB[4];
        issue(lo, gA, wA4, cA);
        int tap = lo;
        for (; tap + 2 <= hi; tap += 2) {
            issue(tap + 1, gB, wB4, cB);
            consume(gA, wA4, cA);
            if (tap + 2 < hi) issue(tap + 2, gA, wA4, cA);
            consume(gB, wB4, cB);
        }
        if (tap < hi) consume(gA, wA4, cA);
    }

    #pragma unroll
    for (int mf = 0; mf < 4; ++mf)
        #pragma unroll
        for (int jj = 0; jj < 4; ++jj) {
            int o = mf * 16 + l4 * 4 + jj;
            atomicAdd(&s_red[pl * 68 + o], dacc[mf][jj]);
        }
    __syncthreads();

    // ---- phase 3: fused epilogue ----
    if (!L2) {
        // leaky-relu + channel-last bf16 store (feeds layer-2 conv + sampling)
        int pp = tid >> 3, o8 = (tid & 7) << 3;
        __hip_bfloat16* dst = ycl + ((((size_t)b * Tc + t) * HW + h * 64 + half * 32 + pp) << 6) + o8;
        bf16x8 o8v;
        #pragma unroll
        for (int jj = 0; jj < 8; ++jj) {
            float v = s_red[pp * 68 + o8 + jj];
            v = v >= 0.f ? v : 0.1f * v;
            o8v[jj] = f2bf(v);
        }
        *reinterpret_cast<bf16x8*>(dst) = o8v;
    } else {
        // residual add + fp32 channel-first store
        int o = tid >> 2, pg = (tid & 3) << 3;
        size_t base = ((size_t)(b * Cc + o) * Tc + t) * HW + h * 64 + half * 32 + pg;
        #pragma unroll
        for (int q = 0; q < 2; ++q) {
            f32x4 r, xv = *reinterpret_cast<const f32x4*>(xres + base + q * 4);
            #pragma unroll
            for (int jj = 0; jj < 4; ++jj) r[jj] = s_red[(pg + q * 4 + jj) * 68 + o] + xv[jj];
            *reinterpret_cast<f32x4*>(outf + base + q * 4) = r;
        }
    }
}

extern "C" void kernel_launch(void* const* d_in, const int* in_sizes, int n_in,
                              void* d_out, int out_size, void* d_ws, size_t ws_size,
                              hipStream_t stream)
{
    const float* x   = (const float*)d_in[0];
    const float* w0  = (const float*)d_in[1];
    const float* ow0 = (const float*)d_in[2];
    const float* ob0 = (const float*)d_in[3];
    const float* w1  = (const float*)d_in[4];
    const float* ow1 = (const float*)d_in[5];
    const float* ob1 = (const float*)d_in[6];
    float* out = (float*)d_out;

    // ws layout (bf16): xcl 2M, ycl 2M, 4 weight buffers 110592 each => ~8.8 MB total
    __hip_bfloat16* xcl  = (__hip_bfloat16*)d_ws;
    __hip_bfloat16* ycl  = xcl  + (size_t)Bc * THW * 64;
    __hip_bfloat16* owA0 = ycl  + (size_t)Bc * THW * 64;
    __hip_bfloat16* owA1 = owA0 + (size_t)216 * 512;
    __hip_bfloat16* wA0  = owA1 + (size_t)216 * 512;
    __hip_bfloat16* wA1  = wA0  + (size_t)216 * 512;

    w_prep<<<432, 256, 0, stream>>>(ow0, owA0, OFFc);
    w_prep<<<432, 256, 0, stream>>>(ow1, owA1, OFFc);
    w_prep<<<432, 256, 0, stream>>>(w0,  wA0,  Cc);
    w_prep<<<432, 256, 0, stream>>>(w1,  wA1,  Cc);
    cast_cl<<<512, 256, 0, stream>>>(x, xcl);

    fused_deform<false><<<1024, 256, 0, stream>>>(xcl, owA0, ob0, wA0, nullptr, nullptr, ycl);
    fused_deform<true><<<1024, 256, 0, stream>>>(ycl, owA1, ob1, wA1, x, out, nullptr);
}